// Round 4
// baseline (215.682 us; speedup 1.0000x reference)
//
#include <hip/hip_runtime.h>

typedef unsigned short u16;
typedef u16   u16x8 __attribute__((ext_vector_type(8)));
typedef short s16x8 __attribute__((ext_vector_type(8)));
typedef float f32x4 __attribute__((ext_vector_type(4)));

__device__ __forceinline__ float b2f(u16 u) {
    return __uint_as_float(((unsigned)u) << 16);
}
__device__ __forceinline__ u16 f2b(float f) {
    unsigned x = __float_as_uint(f);
    x += 0x7fffu + ((x >> 16) & 1u);
    return (u16)(x >> 16);
}
// fast-math-proof finiteness scrub (integer exponent test)
__device__ __forceinline__ float scrub(float v, unsigned bit, unsigned* lf) {
    unsigned u = __float_as_uint(v);
    if (((u >> 23) & 0xFFu) == 0xFFu) { *lf |= bit; return 0.f; }
    return v;
}

#define THETA_SCALE 0.05190512648261f   // log2(10000)/256

// ---------------- probe: decide if inputs are f32 (flag=1) or bf16 (flag=0)
__global__ void k_probe(const u16* __restrict__ x16, unsigned* __restrict__ flag) {
    __shared__ int cnt;
    if (threadIdx.x == 0) cnt = 0;
    __syncthreads();
    int c = 0;
    #pragma unroll
    for (int j = 0; j < 4; ++j) {
        u16 u = x16[threadIdx.x * 4 + j];
        unsigned e = (u >> 7) & 0xFF;
        if (u == 0 || (e >= 97 && e <= 157)) c++;   // |v| in ~[2^-30,2^30] or 0
    }
    atomicAdd(&cnt, c);
    __syncthreads();
    if (threadIdx.x == 0) *flag = (cnt < 922) ? 1u : 0u;   // <90% plausible => f32
}

// ---------------- transpose Wqk [512][1024] -> WThi/WTlo [1024][512] --------
__global__ void k_transpose(const void* __restrict__ W,
                            u16* __restrict__ WThi, u16* __restrict__ WTlo,
                            const unsigned* __restrict__ flagp) {
    const bool isf = (*flagp != 0);
    __shared__ float tile[32][33];
    int c0 = blockIdx.x * 32;
    int r0 = blockIdx.y * 32;
    int tx = threadIdx.x & 31;
    int ty = threadIdx.x >> 5;   // 0..7
    #pragma unroll
    for (int i = 0; i < 4; ++i) {
        int r = ty + i * 8;
        size_t idx = (size_t)(r0 + r) * 1024 + c0 + tx;
        tile[r][tx] = isf ? ((const float*)W)[idx] : b2f(((const u16*)W)[idx]);
    }
    __syncthreads();
    #pragma unroll
    for (int i = 0; i < 4; ++i) {
        int r = ty + i * 8;
        float v = tile[tx][r];
        u16 hi = f2b(v);
        size_t idx = (size_t)(c0 + r) * 512 + r0 + tx;
        WThi[idx] = hi;
        WTlo[idx] = isf ? f2b(v - b2f(hi)) : (u16)0;
    }
}

// ---------------- GEMM (bf16 mode): [16384,512]x[512,1024]+bias, elu+1 -----
#define BM 128
#define BN 128
#define BKK 64
#define LDA 72   // 64 + 8 pad

__global__ __launch_bounds__(256)
void k_gemm_b(const u16* __restrict__ X, const u16* __restrict__ WT,
              const u16* __restrict__ bqk,
              u16* Qo, u16* __restrict__ Kb,
              const unsigned* __restrict__ flagp, unsigned* __restrict__ dbg) {
    if (*flagp != 0) return;   // f32 mode -> other kernel
    __shared__ u16 As[BM * LDA];
    __shared__ u16 Bs[BN * LDA];
    const int t = threadIdx.x;
    const int m0 = blockIdx.x * BM;
    const int n0 = blockIdx.y * BN;
    const int lane = t & 63;
    const int wave = t >> 6;
    const int wm = (wave >> 1) * 64;
    const int wn = (wave & 1) * 64;
    const int quad = lane >> 4;
    const int l16 = lane & 15;
    const int sr = t >> 3;
    const int sc = (t & 7) * 8;

    f32x4 acc[4][4];
    f32x4 zero4 = {0.f, 0.f, 0.f, 0.f};
    #pragma unroll
    for (int i = 0; i < 4; ++i)
        #pragma unroll
        for (int j = 0; j < 4; ++j) acc[i][j] = zero4;

    for (int k0 = 0; k0 < 512; k0 += BKK) {
        __syncthreads();
        #pragma unroll
        for (int cc = 0; cc < 4; ++cc) {
            int row = cc * 32 + sr;
            *(u16x8*)&As[row * LDA + sc] =
                *(const u16x8*)(X + (size_t)(m0 + row) * 512 + k0 + sc);
            *(u16x8*)&Bs[row * LDA + sc] =
                *(const u16x8*)(WT + (size_t)(n0 + row) * 512 + k0 + sc);
        }
        __syncthreads();
        #pragma unroll
        for (int ks = 0; ks < BKK; ks += 32) {
            s16x8 af[4], bf[4];
            #pragma unroll
            for (int i = 0; i < 4; ++i)
                af[i] = *(const s16x8*)&As[(wm + i * 16 + l16) * LDA + ks + quad * 8];
            #pragma unroll
            for (int j = 0; j < 4; ++j)
                bf[j] = *(const s16x8*)&Bs[(wn + j * 16 + l16) * LDA + ks + quad * 8];
            #pragma unroll
            for (int i = 0; i < 4; ++i)
                #pragma unroll
                for (int j = 0; j < 4; ++j)
                    acc[i][j] = __builtin_amdgcn_mfma_f32_16x16x32_bf16(
                        af[i], bf[j], acc[i][j], 0, 0, 0);
        }
    }
    const bool isQ = (n0 < 512);
    const unsigned bit = isQ ? 1u : 2u;
    u16* O = isQ ? Qo : Kb;
    unsigned lf = 0;
    #pragma unroll
    for (int i = 0; i < 4; ++i)
        #pragma unroll
        for (int j = 0; j < 4; ++j) {
            int col = n0 + wn + j * 16 + l16;
            float bias = b2f(bqk[col]);
            int gc = col & 511;
            #pragma unroll
            for (int r = 0; r < 4; ++r) {
                int grow = m0 + wm + i * 16 + quad * 4 + r;
                float v = acc[i][j][r] + bias;
                v = v > 0.f ? v + 1.f : __expf(v);
                v = scrub(v, bit, &lf);
                O[(size_t)grow * 512 + gc] = f2b(v);
            }
        }
    if (lf) atomicOr(dbg, lf);
}

// ---------------- GEMM (f32 mode): hi/lo bf16 split, 3 MFMAs ----------------
__global__ __launch_bounds__(256)
void k_gemm_f(const float* __restrict__ X, const u16* __restrict__ WThi,
              const u16* __restrict__ WTlo, const float* __restrict__ bqk,
              float* Qo, u16* __restrict__ Kb,
              const unsigned* __restrict__ flagp, unsigned* __restrict__ dbg) {
    if (*flagp == 0) return;   // bf16 mode -> other kernel
    __shared__ u16 Ah[BM * LDA];
    __shared__ u16 Al[BM * LDA];
    __shared__ u16 Bh[BN * LDA];
    __shared__ u16 Bl[BN * LDA];
    const int t = threadIdx.x;
    const int m0 = blockIdx.x * BM;
    const int n0 = blockIdx.y * BN;
    const int lane = t & 63;
    const int wave = t >> 6;
    const int wm = (wave >> 1) * 64;
    const int wn = (wave & 1) * 64;
    const int quad = lane >> 4;
    const int l16 = lane & 15;
    const int sr = t >> 3;
    const int sc = (t & 7) * 8;

    f32x4 acc[4][4];
    f32x4 zero4 = {0.f, 0.f, 0.f, 0.f};
    #pragma unroll
    for (int i = 0; i < 4; ++i)
        #pragma unroll
        for (int j = 0; j < 4; ++j) acc[i][j] = zero4;

    for (int k0 = 0; k0 < 512; k0 += BKK) {
        __syncthreads();
        #pragma unroll
        for (int cc = 0; cc < 4; ++cc) {
            int row = cc * 32 + sr;
            const float* ap = X + (size_t)(m0 + row) * 512 + k0 + sc;
            float4 a0 = *(const float4*)ap;
            float4 a1 = *(const float4*)(ap + 4);
            float av[8] = {a0.x, a0.y, a0.z, a0.w, a1.x, a1.y, a1.z, a1.w};
            u16x8 hv, lv;
            #pragma unroll
            for (int j = 0; j < 8; ++j) {
                u16 hi = f2b(av[j]);
                hv[j] = hi;
                lv[j] = f2b(av[j] - b2f(hi));
            }
            *(u16x8*)&Ah[row * LDA + sc] = hv;
            *(u16x8*)&Al[row * LDA + sc] = lv;
            size_t widx = (size_t)(n0 + row) * 512 + k0 + sc;
            *(u16x8*)&Bh[row * LDA + sc] = *(const u16x8*)(WThi + widx);
            *(u16x8*)&Bl[row * LDA + sc] = *(const u16x8*)(WTlo + widx);
        }
        __syncthreads();
        #pragma unroll
        for (int ks = 0; ks < BKK; ks += 32) {
            s16x8 ah[4], al[4], bh[4], bl[4];
            #pragma unroll
            for (int i = 0; i < 4; ++i) {
                int off = (wm + i * 16 + l16) * LDA + ks + quad * 8;
                ah[i] = *(const s16x8*)&Ah[off];
                al[i] = *(const s16x8*)&Al[off];
            }
            #pragma unroll
            for (int j = 0; j < 4; ++j) {
                int off = (wn + j * 16 + l16) * LDA + ks + quad * 8;
                bh[j] = *(const s16x8*)&Bh[off];
                bl[j] = *(const s16x8*)&Bl[off];
            }
            #pragma unroll
            for (int i = 0; i < 4; ++i)
                #pragma unroll
                for (int j = 0; j < 4; ++j) {
                    acc[i][j] = __builtin_amdgcn_mfma_f32_16x16x32_bf16(
                        ah[i], bh[j], acc[i][j], 0, 0, 0);
                    acc[i][j] = __builtin_amdgcn_mfma_f32_16x16x32_bf16(
                        ah[i], bl[j], acc[i][j], 0, 0, 0);
                    acc[i][j] = __builtin_amdgcn_mfma_f32_16x16x32_bf16(
                        al[i], bh[j], acc[i][j], 0, 0, 0);
                }
        }
    }
    const bool isQ = (n0 < 512);
    const unsigned bit = isQ ? 1u : 2u;
    unsigned lf = 0;
    #pragma unroll
    for (int i = 0; i < 4; ++i)
        #pragma unroll
        for (int j = 0; j < 4; ++j) {
            int col = n0 + wn + j * 16 + l16;
            float bias = bqk[col];
            int gc = col & 511;
            #pragma unroll
            for (int r = 0; r < 4; ++r) {
                int grow = m0 + wm + i * 16 + quad * 4 + r;
                float v = acc[i][j][r] + bias;
                v = v > 0.f ? v + 1.f : __expf(v);
                v = scrub(v, bit, &lf);
                if (isQ) Qo[(size_t)grow * 512 + gc] = v;
                else     Kb[(size_t)grow * 512 + gc] = f2b(v);
            }
        }
    if (lf) atomicOr(dbg, lf);
}

// ---------------- kv[b,h,d,e] = sum_n k_rope*v ; ksum[b,h,d] = sum_n k ------
__global__ __launch_bounds__(256)
void k_kv(const u16* __restrict__ Kb, const void* __restrict__ X,
          float* __restrict__ kvbuf, float* __restrict__ ksum,
          const unsigned* __restrict__ flagp, unsigned* __restrict__ dbg) {
    const bool isf = (*flagp != 0);
    const int bh = blockIdx.x;
    const int b = bh >> 4, h = bh & 15;
    const int nb = blockIdx.y * 512;
    __shared__ float kr_s[64 * 32];
    __shared__ float v_s[64 * 32];
    const int t = threadIdx.x;
    const int row = t >> 2;
    const int c8 = (t & 3) * 8;
    const int d = t >> 3;
    const int e0 = (t & 7) * 4;
    float ksl[8] = {0, 0, 0, 0, 0, 0, 0, 0};
    float acc[4] = {0, 0, 0, 0};
    unsigned lf = 0;

    float th[4];
    #pragma unroll
    for (int p = 0; p < 4; ++p)
        th[p] = exp2f(-THETA_SCALE * (float)(h * 16 + (c8 >> 1) + p));

    for (int pass = 0; pass < 8; ++pass) {
        int n = nb + pass * 64 + row;
        size_t base = (size_t)(b * 4096 + n) * 512 + h * 32 + c8;
        u16x8 k8 = *(const u16x8*)(Kb + base);
        float kf[8], vf[8], kr[8];
        if (isf) {
            float4 v0 = *(const float4*)((const float*)X + base);
            float4 v1 = *(const float4*)((const float*)X + base + 4);
            vf[0] = v0.x; vf[1] = v0.y; vf[2] = v0.z; vf[3] = v0.w;
            vf[4] = v1.x; vf[5] = v1.y; vf[6] = v1.z; vf[7] = v1.w;
        } else {
            u16x8 v8 = *(const u16x8*)((const u16*)X + base);
            #pragma unroll
            for (int j = 0; j < 8; ++j) vf[j] = b2f(v8[j]);
        }
        #pragma unroll
        for (int j = 0; j < 8; ++j) {
            kf[j] = scrub(b2f(k8[j]), 4u, &lf);
            vf[j] = scrub(vf[j], 8u, &lf);
        }
        #pragma unroll
        for (int p = 0; p < 4; ++p) {
            float sv, cv;
            sincosf((float)n * th[p], &sv, &cv);
            kr[2 * p]     = kf[2 * p] * cv - kf[2 * p + 1] * sv;
            kr[2 * p + 1] = kf[2 * p] * sv + kf[2 * p + 1] * cv;
        }
        #pragma unroll
        for (int j = 0; j < 8; ++j) ksl[j] += kf[j];
        if (pass) __syncthreads();
        *(float4*)&kr_s[row * 32 + c8]     = make_float4(kr[0], kr[1], kr[2], kr[3]);
        *(float4*)&kr_s[row * 32 + c8 + 4] = make_float4(kr[4], kr[5], kr[6], kr[7]);
        *(float4*)&v_s[row * 32 + c8]      = make_float4(vf[0], vf[1], vf[2], vf[3]);
        *(float4*)&v_s[row * 32 + c8 + 4]  = make_float4(vf[4], vf[5], vf[6], vf[7]);
        __syncthreads();
        #pragma unroll 8
        for (int r = 0; r < 64; ++r) {
            float kd = kr_s[r * 32 + d];
            const float4 vv = *(const float4*)&v_s[r * 32 + e0];
            acc[0] += kd * vv.x;
            acc[1] += kd * vv.y;
            acc[2] += kd * vv.z;
            acc[3] += kd * vv.w;
        }
    }
    __syncthreads();
    *(float4*)&kr_s[row * 32 + c8]     = make_float4(ksl[0], ksl[1], ksl[2], ksl[3]);
    *(float4*)&kr_s[row * 32 + c8 + 4] = make_float4(ksl[4], ksl[5], ksl[6], ksl[7]);
    __syncthreads();
    if (t < 32) {
        float s = 0.f;
        for (int r = 0; r < 64; ++r) s += kr_s[r * 32 + t];
        atomicAdd(&ksum[bh * 32 + t], scrub(s, 16u, &lf));
    }
    #pragma unroll
    for (int j = 0; j < 4; ++j)
        atomicAdd(&kvbuf[(size_t)bh * 1024 + d * 32 + e0 + j], scrub(acc[j], 16u, &lf));
    if (lf) atomicOr(dbg, lf);
}

// ---------------- out = z * (q_rope @ kv)/N + lepe --------------------------
// QO holds Q on entry (bf16 or f32 per mode) and the final output on exit.
__global__ __launch_bounds__(256)
void k_out(void* QO, const void* __restrict__ X,
           const float* __restrict__ kvbuf, const float* __restrict__ ksum,
           const void* __restrict__ lw, const void* __restrict__ lb,
           const unsigned* __restrict__ flagp, unsigned* __restrict__ dbg) {
    const bool isf = (*flagp != 0);
    const int b = blockIdx.x >> 6;
    const int nb = (blockIdx.x & 63) * 64;
    const int hbase = blockIdx.y * 4;
    __shared__ float kv_s[32 * 36];
    __shared__ float qr_s[64 * 36];
    __shared__ float ks_s[32];
    __shared__ float z_s[64];
    const int t = threadIdx.x;
    const int row = t >> 2;
    const int c4 = t & 3;
    const int e0 = c4 * 8;
    const float invN = 1.f / 4096.f;
    const int n = nb + row;
    const size_t rowbase = (size_t)(b * 4096 + n) * 512;
    unsigned lf = 0;

    for (int hh = 0; hh < 4; ++hh) {
        const int h = hbase + hh;
        const int bh = b * 16 + h;
        if (hh) __syncthreads();
        #pragma unroll
        for (int i = 0; i < 4; ++i) {
            int id = t + i * 256;
            kv_s[(id >> 5) * 36 + (id & 31)] =
                scrub(kvbuf[(size_t)bh * 1024 + id] * invN, 64u, &lf);
        }
        if (t < 32) ks_s[t] = scrub(ksum[bh * 32 + t] * invN, 64u, &lf);
        __syncthreads();

        float qf[8];
        if (isf) {
            const float* qp = (const float*)QO + rowbase + h * 32 + e0;
            float4 q0 = *(const float4*)qp;
            float4 q1 = *(const float4*)(qp + 4);
            qf[0] = q0.x; qf[1] = q0.y; qf[2] = q0.z; qf[3] = q0.w;
            qf[4] = q1.x; qf[5] = q1.y; qf[6] = q1.z; qf[7] = q1.w;
        } else {
            u16x8 q8 = *(const u16x8*)((const u16*)QO + rowbase + h * 32 + e0);
            #pragma unroll
            for (int j = 0; j < 8; ++j) qf[j] = b2f(q8[j]);
        }
        #pragma unroll
        for (int j = 0; j < 8; ++j) qf[j] = scrub(qf[j], 32u, &lf);
        float part = 0.f;
        #pragma unroll
        for (int j = 0; j < 8; ++j) part += qf[j] * ks_s[e0 + j];
        float qr[8];
        #pragma unroll
        for (int p = 0; p < 4; ++p) {
            float th = exp2f(-THETA_SCALE * (float)(h * 16 + c4 * 4 + p));
            float sv, cv;
            sincosf((float)n * th, &sv, &cv);
            qr[2 * p]     = qf[2 * p] * cv - qf[2 * p + 1] * sv;
            qr[2 * p + 1] = qf[2 * p] * sv + qf[2 * p + 1] * cv;
        }
        *(float4*)&qr_s[row * 36 + e0]     = make_float4(qr[0], qr[1], qr[2], qr[3]);
        *(float4*)&qr_s[row * 36 + e0 + 4] = make_float4(qr[4], qr[5], qr[6], qr[7]);
        part += __shfl_xor(part, 1);
        part += __shfl_xor(part, 2);
        if (c4 == 0) z_s[row] = 1.f / (part + 1e-6f);
        __syncthreads();

        float o[8] = {0, 0, 0, 0, 0, 0, 0, 0};
        #pragma unroll 4
        for (int dd = 0; dd < 32; ++dd) {
            float qd = qr_s[row * 36 + dd];
            const float4 k0v = *(const float4*)&kv_s[dd * 36 + e0];
            const float4 k1v = *(const float4*)&kv_s[dd * 36 + e0 + 4];
            o[0] += qd * k0v.x; o[1] += qd * k0v.y; o[2] += qd * k0v.z; o[3] += qd * k0v.w;
            o[4] += qd * k1v.x; o[5] += qd * k1v.y; o[6] += qd * k1v.z; o[7] += qd * k1v.w;
        }
        const float z = z_s[row];

        const int cb = h * 32 + e0;
        float xm[8], xc[8], xp[8], wv0[8], wv1[8], wv2[8], bv[8];
        #pragma unroll
        for (int j = 0; j < 8; ++j) { xm[j] = 0.f; xp[j] = 0.f; }
        if (isf) {
            const float* Xf = (const float*)X;
            #pragma unroll
            for (int j = 0; j < 8; ++j) xc[j] = Xf[rowbase + cb + j];
            if (n > 0)
                #pragma unroll
                for (int j = 0; j < 8; ++j) xm[j] = Xf[rowbase - 512 + cb + j];
            if (n < 4095)
                #pragma unroll
                for (int j = 0; j < 8; ++j) xp[j] = Xf[rowbase + 512 + cb + j];
            const float* lwf = (const float*)lw;
            const float* lbf = (const float*)lb;
            #pragma unroll
            for (int j = 0; j < 8; ++j) {
                int c = cb + j;
                wv0[j] = lwf[c * 3]; wv1[j] = lwf[c * 3 + 1]; wv2[j] = lwf[c * 3 + 2];
                bv[j] = lbf[c];
            }
        } else {
            const u16* Xu = (const u16*)X;
            u16x8 a = *(const u16x8*)(Xu + rowbase + cb);
            #pragma unroll
            for (int j = 0; j < 8; ++j) xc[j] = b2f(a[j]);
            if (n > 0) {
                u16x8 m8 = *(const u16x8*)(Xu + rowbase - 512 + cb);
                #pragma unroll
                for (int j = 0; j < 8; ++j) xm[j] = b2f(m8[j]);
            }
            if (n < 4095) {
                u16x8 p8 = *(const u16x8*)(Xu + rowbase + 512 + cb);
                #pragma unroll
                for (int j = 0; j < 8; ++j) xp[j] = b2f(p8[j]);
            }
            const u16* lwu = (const u16*)lw;
            const u16* lbu = (const u16*)lb;
            #pragma unroll
            for (int j = 0; j < 8; ++j) {
                int c = cb + j;
                wv0[j] = b2f(lwu[c * 3]); wv1[j] = b2f(lwu[c * 3 + 1]);
                wv2[j] = b2f(lwu[c * 3 + 2]); bv[j] = b2f(lbu[c]);
            }
        }
        float rv[8];
        #pragma unroll
        for (int j = 0; j < 8; ++j) {
            float lep = xm[j] * wv0[j] + xc[j] * wv1[j] + xp[j] * wv2[j] + bv[j];
            rv[j] = scrub(o[j] * z + lep, 128u, &lf);
        }
        if (isf) {
            float* Of = (float*)QO + rowbase + cb;
            *(float4*)Of       = make_float4(rv[0], rv[1], rv[2], rv[3]);
            *(float4*)(Of + 4) = make_float4(rv[4], rv[5], rv[6], rv[7]);
        } else {
            u16x8 res;
            #pragma unroll
            for (int j = 0; j < 8; ++j) res[j] = f2b(rv[j]);
            *(u16x8*)((u16*)QO + rowbase + cb) = res;
        }
    }
    if (lf) atomicOr(dbg, lf);
}

// ---------------- diagnostic: sentinel (stage flags | mode<<8) into out[0] --
__global__ void k_report(const unsigned* __restrict__ flagp,
                         const unsigned* __restrict__ dbg, void* out) {
    unsigned f = *dbg;
    if (f) {
        unsigned code = f | (*flagp ? 0x100u : 0u);
        float s = 1000.0f * (float)code;
        if (*flagp) ((float*)out)[0] = s;
        else        ((u16*)out)[0] = f2b(s);
    }
}

extern "C" void kernel_launch(void* const* d_in, const int* in_sizes, int n_in,
                              void* d_out, int out_size, void* d_ws, size_t ws_size,
                              hipStream_t stream) {
    const void* x   = d_in[0];   // (4,4096,512)
    const void* Wqk = d_in[1];   // (512,1024)
    const void* bqk = d_in[2];   // (1024,)
    const void* lw  = d_in[3];   // (512,1,3)
    const void* lb  = d_in[4];   // (512,)

    // workspace layout (~18.3 MB)
    char* w = (char*)d_ws;
    u16* Kb      = (u16*)w;   w += (size_t)16384 * 512 * 2;   // 16 MB
    u16* WThi    = (u16*)w;   w += (size_t)1024 * 512 * 2;    // 1 MB
    u16* WTlo    = (u16*)w;   w += (size_t)1024 * 512 * 2;    // 1 MB
    float* kvbuf = (float*)w; w += (size_t)64 * 1024 * 4;     // 256 KB
    float* ksum  = (float*)w; w += (size_t)64 * 32 * 4;       // 8 KB
    unsigned* flag = (unsigned*)w;                            // 4 B
    unsigned* dbg  = (unsigned*)(w + 4);                      // 4 B

    hipMemsetAsync(kvbuf, 0,
                   (size_t)64 * 1024 * 4 + (size_t)64 * 32 * 4 + 64, stream);
    k_probe<<<1, 256, 0, stream>>>((const u16*)x, flag);
    k_transpose<<<dim3(32, 16), 256, 0, stream>>>(Wqk, WThi, WTlo, flag);
    k_gemm_b<<<dim3(128, 8), 256, 0, stream>>>((const u16*)x, WThi, (const u16*)bqk,
                                               (u16*)d_out, Kb, flag, dbg);
    k_gemm_f<<<dim3(128, 8), 256, 0, stream>>>((const float*)x, WThi, WTlo,
                                               (const float*)bqk,
                                               (float*)d_out, Kb, flag, dbg);
    k_kv<<<dim3(64, 8), 256, 0, stream>>>(Kb, x, kvbuf, ksum, flag, dbg);
    k_out<<<dim3(256, 4), 256, 0, stream>>>(d_out, x, kvbuf, ksum, lw, lb, flag, dbg);
    k_report<<<1, 1, 0, stream>>>(flag, dbg, d_out);
}

// Round 5
// 188.450 us; speedup vs baseline: 1.1445x; 1.1445x over previous
//
#include <hip/hip_runtime.h>

typedef unsigned short u16;
typedef u16   u16x8 __attribute__((ext_vector_type(8)));
typedef short s16x8 __attribute__((ext_vector_type(8)));
typedef float f32x4 __attribute__((ext_vector_type(4)));

__device__ __forceinline__ float b2f(u16 u) {
    return __uint_as_float(((unsigned)u) << 16);
}
__device__ __forceinline__ u16 f2b(float f) {
    unsigned x = __float_as_uint(f);
    x += 0x7fffu + ((x >> 16) & 1u);
    return (u16)(x >> 16);
}
// async global->LDS, 16B per lane; LDS dest = wave-uniform base + lane*16
__device__ __forceinline__ void gload_lds(const u16* g, u16* l) {
    __builtin_amdgcn_global_load_lds(
        (const __attribute__((address_space(1))) unsigned int*)g,
        (__attribute__((address_space(3))) unsigned int*)l, 16, 0, 0);
}

#define THETA_SCALE 0.05190512648261f   // log2(10000)/256

// ---------------- Xb = bf16(x), 8 elems/thread ------------------------------
__global__ __launch_bounds__(256)
void k_xbf(const float* __restrict__ X, u16* __restrict__ Xb) {
    size_t i = (size_t)(blockIdx.x * 256 + threadIdx.x) * 8;
    float4 a = *(const float4*)(X + i);
    float4 b = *(const float4*)(X + i + 4);
    u16x8 r;
    r[0] = f2b(a.x); r[1] = f2b(a.y); r[2] = f2b(a.z); r[3] = f2b(a.w);
    r[4] = f2b(b.x); r[5] = f2b(b.y); r[6] = f2b(b.z); r[7] = f2b(b.w);
    *(u16x8*)(Xb + i) = r;
}

// ---------------- transpose Wqk f32 [512][1024] -> WThi/WTlo bf16 [1024][512]
__global__ void k_transpose(const float* __restrict__ W,
                            u16* __restrict__ WThi, u16* __restrict__ WTlo) {
    __shared__ float tile[32][33];
    int c0 = blockIdx.x * 32;
    int r0 = blockIdx.y * 32;
    int tx = threadIdx.x & 31;
    int ty = threadIdx.x >> 5;   // 0..7
    #pragma unroll
    for (int i = 0; i < 4; ++i) {
        int r = ty + i * 8;
        tile[r][tx] = W[(size_t)(r0 + r) * 1024 + c0 + tx];
    }
    __syncthreads();
    #pragma unroll
    for (int i = 0; i < 4; ++i) {
        int r = ty + i * 8;
        float v = tile[tx][r];
        u16 hi = f2b(v);
        size_t idx = (size_t)(c0 + r) * 512 + r0 + tx;
        WThi[idx] = hi;
        WTlo[idx] = f2b(v - b2f(hi));
    }
}

// ---------------- GEMM: Xb[16384,512](bf16) x (WThi+WTlo)[512,1024] + bias,
//                  elu+1; cols<512 -> Q (f32, in d_out), cols>=512 -> K (bf16)
__global__ __launch_bounds__(256)
void k_gemm(const u16* __restrict__ Xb, const u16* __restrict__ WTh,
            const u16* __restrict__ WTl, const float* __restrict__ bqk,
            float* __restrict__ Qo, u16* __restrict__ Kb) {
    __shared__ u16 As[128 * 64];   // unpadded: required by global_load_lds
    __shared__ u16 Bh[128 * 64];
    __shared__ u16 Bl[128 * 64];
    const int t = threadIdx.x;
    const int m0 = blockIdx.x * 128;
    const int n0 = blockIdx.y * 128;
    const int lane = t & 63;
    const int wave = t >> 6;
    const int wm = (wave >> 1) * 64;
    const int wn = (wave & 1) * 64;
    const int quad = lane >> 4;
    const int l16 = lane & 15;
    const int lr = lane >> 3;          // 0..7: row within 8-row group
    const int lc = (lane & 7) * 8;     // col offset (8 bf16 = 16 B)

    f32x4 acc[4][4];
    f32x4 zero4 = {0.f, 0.f, 0.f, 0.f};
    #pragma unroll
    for (int i = 0; i < 4; ++i)
        #pragma unroll
        for (int j = 0; j < 4; ++j) acc[i][j] = zero4;

    for (int k0 = 0; k0 < 512; k0 += 64) {
        __syncthreads();   // previous tile's LDS reads done
        #pragma unroll
        for (int g = 0; g < 4; ++g) {
            int r0 = wave * 32 + g * 8;
            size_t ga = (size_t)(m0 + r0 + lr) * 512 + k0 + lc;
            size_t gb = (size_t)(n0 + r0 + lr) * 512 + k0 + lc;
            gload_lds(Xb + ga, &As[r0 * 64]);
            gload_lds(WTh + gb, &Bh[r0 * 64]);
            gload_lds(WTl + gb, &Bl[r0 * 64]);
        }
        __syncthreads();   // drains vmcnt -> staged data visible
        #pragma unroll
        for (int ks = 0; ks < 64; ks += 32) {
            s16x8 a4[4], bh4[4], bl4[4];
            #pragma unroll
            for (int i = 0; i < 4; ++i)
                a4[i] = *(const s16x8*)&As[(wm + i * 16 + l16) * 64 + ks + quad * 8];
            #pragma unroll
            for (int j = 0; j < 4; ++j) {
                int off = (wn + j * 16 + l16) * 64 + ks + quad * 8;
                bh4[j] = *(const s16x8*)&Bh[off];
                bl4[j] = *(const s16x8*)&Bl[off];
            }
            #pragma unroll
            for (int i = 0; i < 4; ++i)
                #pragma unroll
                for (int j = 0; j < 4; ++j) {
                    acc[i][j] = __builtin_amdgcn_mfma_f32_16x16x32_bf16(
                        a4[i], bh4[j], acc[i][j], 0, 0, 0);
                    acc[i][j] = __builtin_amdgcn_mfma_f32_16x16x32_bf16(
                        a4[i], bl4[j], acc[i][j], 0, 0, 0);
                }
        }
    }

    const bool isQ = (n0 < 512);   // block-uniform
    #pragma unroll
    for (int i = 0; i < 4; ++i)
        #pragma unroll
        for (int j = 0; j < 4; ++j) {
            int col = n0 + wn + j * 16 + l16;
            float bias = bqk[col];
            int gc = col & 511;
            #pragma unroll
            for (int r = 0; r < 4; ++r) {
                int grow = m0 + wm + i * 16 + quad * 4 + r;
                float v = acc[i][j][r] + bias;
                v = v > 0.f ? v + 1.f : __expf(v);   // elu(v)+1
                if (isQ) Qo[(size_t)grow * 512 + gc] = v;
                else     Kb[(size_t)grow * 512 + gc] = f2b(v);
            }
        }
}

// ---------------- kv[b,h,d,e] = sum_n k_rope*v ; ksum[b,h,d] = sum_n k ------
__global__ __launch_bounds__(256)
void k_kv(const u16* __restrict__ Kb, const u16* __restrict__ Xb,
          float* __restrict__ kvbuf, float* __restrict__ ksum) {
    const int bh = blockIdx.x;            // 0..63
    const int b = bh >> 4, h = bh & 15;
    const int nb = blockIdx.y * 512;      // N chunk
    __shared__ float kr_s[64 * 32];
    __shared__ float v_s[64 * 32];
    const int t = threadIdx.x;
    const int row = t >> 2;               // 0..63 (staging row)
    const int c8 = (t & 3) * 8;           // channel chunk
    const int d = t >> 3;                 // 0..31 (compute)
    const int e0 = (t & 7) * 4;
    float ksl[8] = {0, 0, 0, 0, 0, 0, 0, 0};
    float acc[4] = {0, 0, 0, 0};

    float th[4];
    #pragma unroll
    for (int p = 0; p < 4; ++p)
        th[p] = exp2f(-THETA_SCALE * (float)(h * 16 + (c8 >> 1) + p));

    for (int pass = 0; pass < 8; ++pass) {
        int n = nb + pass * 64 + row;
        size_t base = (size_t)(b * 4096 + n) * 512 + h * 32 + c8;
        u16x8 k8 = *(const u16x8*)(Kb + base);
        u16x8 v8 = *(const u16x8*)(Xb + base);
        float kf[8], vf[8], kr[8];
        #pragma unroll
        for (int j = 0; j < 8; ++j) { kf[j] = b2f(k8[j]); vf[j] = b2f(v8[j]); }
        #pragma unroll
        for (int p = 0; p < 4; ++p) {
            float sv, cv;
            sincosf((float)n * th[p], &sv, &cv);
            kr[2 * p]     = kf[2 * p] * cv - kf[2 * p + 1] * sv;
            kr[2 * p + 1] = kf[2 * p] * sv + kf[2 * p + 1] * cv;
        }
        #pragma unroll
        for (int j = 0; j < 8; ++j) ksl[j] += kf[j];
        if (pass) __syncthreads();
        *(float4*)&kr_s[row * 32 + c8]     = make_float4(kr[0], kr[1], kr[2], kr[3]);
        *(float4*)&kr_s[row * 32 + c8 + 4] = make_float4(kr[4], kr[5], kr[6], kr[7]);
        *(float4*)&v_s[row * 32 + c8]      = make_float4(vf[0], vf[1], vf[2], vf[3]);
        *(float4*)&v_s[row * 32 + c8 + 4]  = make_float4(vf[4], vf[5], vf[6], vf[7]);
        __syncthreads();
        #pragma unroll 8
        for (int r = 0; r < 64; ++r) {
            float kd = kr_s[r * 32 + d];
            const float4 vv = *(const float4*)&v_s[r * 32 + e0];
            acc[0] += kd * vv.x;
            acc[1] += kd * vv.y;
            acc[2] += kd * vv.z;
            acc[3] += kd * vv.w;
        }
    }
    __syncthreads();
    *(float4*)&kr_s[row * 32 + c8]     = make_float4(ksl[0], ksl[1], ksl[2], ksl[3]);
    *(float4*)&kr_s[row * 32 + c8 + 4] = make_float4(ksl[4], ksl[5], ksl[6], ksl[7]);
    __syncthreads();
    if (t < 32) {
        float s = 0.f;
        for (int r = 0; r < 64; ++r) s += kr_s[r * 32 + t];
        atomicAdd(&ksum[bh * 32 + t], s);
    }
    #pragma unroll
    for (int j = 0; j < 4; ++j)
        atomicAdd(&kvbuf[(size_t)bh * 1024 + d * 32 + e0 + j], acc[j]);
}

// ---------------- out = z * (q_rope @ kv)/N + lepe (f32 in/out in d_out) ----
__global__ __launch_bounds__(256)
void k_out(float* QO, const u16* __restrict__ Xb,
           const float* __restrict__ kvbuf, const float* __restrict__ ksum,
           const float* __restrict__ lw, const float* __restrict__ lb) {
    const int b = blockIdx.x >> 6;
    const int nb = (blockIdx.x & 63) * 64;
    const int hbase = blockIdx.y * 4;
    __shared__ float kv_s[32 * 36];
    __shared__ float qr_s[64 * 36];
    __shared__ float ks_s[32];
    __shared__ float z_s[64];
    const int t = threadIdx.x;
    const int row = t >> 2;          // 0..63 local n
    const int c4 = t & 3;
    const int e0 = c4 * 8;
    const float invN = 1.f / 4096.f;
    const int n = nb + row;
    const size_t rowbase = (size_t)(b * 4096 + n) * 512;

    for (int hh = 0; hh < 4; ++hh) {
        const int h = hbase + hh;
        const int bh = b * 16 + h;
        if (hh) __syncthreads();               // protect LDS reuse
        #pragma unroll
        for (int i = 0; i < 4; ++i) {
            int id = t + i * 256;              // 0..1023
            kv_s[(id >> 5) * 36 + (id & 31)] = kvbuf[(size_t)bh * 1024 + id] * invN;
        }
        if (t < 32) ks_s[t] = ksum[bh * 32 + t] * invN;   // kmean
        __syncthreads();

        // phase 1: q (f32 from d_out), z partial dot, rope, stage q_rope
        const float* qp = QO + rowbase + h * 32 + e0;
        float4 q0 = *(const float4*)qp;
        float4 q1 = *(const float4*)(qp + 4);
        float qf[8] = {q0.x, q0.y, q0.z, q0.w, q1.x, q1.y, q1.z, q1.w};
        float part = 0.f;
        #pragma unroll
        for (int j = 0; j < 8; ++j) part += qf[j] * ks_s[e0 + j];
        float qr[8];
        #pragma unroll
        for (int p = 0; p < 4; ++p) {
            float th = exp2f(-THETA_SCALE * (float)(h * 16 + c4 * 4 + p));
            float sv, cv;
            sincosf((float)n * th, &sv, &cv);
            qr[2 * p]     = qf[2 * p] * cv - qf[2 * p + 1] * sv;
            qr[2 * p + 1] = qf[2 * p] * sv + qf[2 * p + 1] * cv;
        }
        *(float4*)&qr_s[row * 36 + e0]     = make_float4(qr[0], qr[1], qr[2], qr[3]);
        *(float4*)&qr_s[row * 36 + e0 + 4] = make_float4(qr[4], qr[5], qr[6], qr[7]);
        part += __shfl_xor(part, 1);
        part += __shfl_xor(part, 2);
        if (c4 == 0) z_s[row] = 1.f / (part + 1e-6f);
        __syncthreads();

        // phase 2: out[e0..e0+7] = z * sum_d qr[d]*kv[d][e]
        float o[8] = {0, 0, 0, 0, 0, 0, 0, 0};
        #pragma unroll 4
        for (int dd = 0; dd < 32; ++dd) {
            float qd = qr_s[row * 36 + dd];
            const float4 k0v = *(const float4*)&kv_s[dd * 36 + e0];
            const float4 k1v = *(const float4*)&kv_s[dd * 36 + e0 + 4];
            o[0] += qd * k0v.x; o[1] += qd * k0v.y; o[2] += qd * k0v.z; o[3] += qd * k0v.w;
            o[4] += qd * k1v.x; o[5] += qd * k1v.y; o[6] += qd * k1v.z; o[7] += qd * k1v.w;
        }
        const float z = z_s[row];

        // lepe: depthwise conv k=3, pad 1 (per-batch), + bias; x via Xb bf16
        const int cb = h * 32 + e0;
        u16x8 xc = *(const u16x8*)(Xb + rowbase + cb);
        u16x8 xm = {0, 0, 0, 0, 0, 0, 0, 0};
        u16x8 xp = {0, 0, 0, 0, 0, 0, 0, 0};
        if (n > 0)    xm = *(const u16x8*)(Xb + rowbase - 512 + cb);
        if (n < 4095) xp = *(const u16x8*)(Xb + rowbase + 512 + cb);
        float rv[8];
        #pragma unroll
        for (int j = 0; j < 8; ++j) {
            int c = cb + j;
            float lep = b2f(xm[j]) * lw[c * 3] +
                        b2f(xc[j]) * lw[c * 3 + 1] +
                        b2f(xp[j]) * lw[c * 3 + 2] + lb[c];
            rv[j] = o[j] * z + lep;
        }
        float* Of = QO + rowbase + cb;   // same thread read q above -> safe
        *(float4*)Of       = make_float4(rv[0], rv[1], rv[2], rv[3]);
        *(float4*)(Of + 4) = make_float4(rv[4], rv[5], rv[6], rv[7]);
    }
}

extern "C" void kernel_launch(void* const* d_in, const int* in_sizes, int n_in,
                              void* d_out, int out_size, void* d_ws, size_t ws_size,
                              hipStream_t stream) {
    const float* x   = (const float*)d_in[0];   // (4,4096,512) f32
    const float* Wqk = (const float*)d_in[1];   // (512,1024)
    const float* bqk = (const float*)d_in[2];   // (1024,)
    const float* lw  = (const float*)d_in[3];   // (512,1,3)
    const float* lb  = (const float*)d_in[4];   // (512,)
    float* out = (float*)d_out;                 // Q then final output (32 MB)

    // workspace layout (~34.3 MB)
    char* w = (char*)d_ws;
    u16* Kb      = (u16*)w;   w += (size_t)16384 * 512 * 2;   // 16 MB
    u16* Xb      = (u16*)w;   w += (size_t)16384 * 512 * 2;   // 16 MB
    u16* WThi    = (u16*)w;   w += (size_t)1024 * 512 * 2;    // 1 MB
    u16* WTlo    = (u16*)w;   w += (size_t)1024 * 512 * 2;    // 1 MB
    float* kvbuf = (float*)w; w += (size_t)64 * 1024 * 4;     // 256 KB
    float* ksum  = (float*)w;                                 // 8 KB

    hipMemsetAsync(kvbuf, 0, (size_t)64 * 1024 * 4 + (size_t)64 * 32 * 4, stream);
    k_xbf<<<4096, 256, 0, stream>>>(x, Xb);
    k_transpose<<<dim3(32, 16), 256, 0, stream>>>(Wqk, WThi, WTlo);
    k_gemm<<<dim3(128, 8), 256, 0, stream>>>(Xb, WThi, WTlo, bqk, out, Kb);
    k_kv<<<dim3(64, 8), 256, 0, stream>>>(Kb, Xb, kvbuf, ksum);
    k_out<<<dim3(256, 4), 256, 0, stream>>>(out, Xb, kvbuf, ksum, lw, lb);
}

// Round 6
// 178.160 us; speedup vs baseline: 1.2106x; 1.0578x over previous
//
#include <hip/hip_runtime.h>

typedef unsigned short u16;
typedef u16   u16x8 __attribute__((ext_vector_type(8)));
typedef short s16x8 __attribute__((ext_vector_type(8)));
typedef float f32x4 __attribute__((ext_vector_type(4)));

__device__ __forceinline__ float b2f(u16 u) {
    return __uint_as_float(((unsigned)u) << 16);
}
__device__ __forceinline__ u16 f2b(float f) {
    unsigned x = __float_as_uint(f);
    x += 0x7fffu + ((x >> 16) & 1u);
    return (u16)(x >> 16);
}
// async global->LDS, 16B per lane; LDS dest = wave-uniform base + lane*16
__device__ __forceinline__ void gload_lds(const u16* g, u16* l) {
    __builtin_amdgcn_global_load_lds(
        (const __attribute__((address_space(1))) unsigned int*)g,
        (__attribute__((address_space(3))) unsigned int*)l, 16, 0, 0);
}

#define THETA_SCALE 0.05190512648261f   // log2(10000)/256

// ---------------- prep: Xb = bf16(x)  +  WT = bf16(Wqk^T) -------------------
// blocks [0,4096): cast 8 elems/thread; blocks [4096,4608): transpose 32x32
__global__ __launch_bounds__(256)
void k_prep(const float* __restrict__ X, u16* __restrict__ Xb,
            const float* __restrict__ W, u16* __restrict__ WT) {
    if (blockIdx.x < 4096) {
        size_t i = (size_t)(blockIdx.x * 256 + threadIdx.x) * 8;
        float4 a = *(const float4*)(X + i);
        float4 b = *(const float4*)(X + i + 4);
        u16x8 r;
        r[0] = f2b(a.x); r[1] = f2b(a.y); r[2] = f2b(a.z); r[3] = f2b(a.w);
        r[4] = f2b(b.x); r[5] = f2b(b.y); r[6] = f2b(b.z); r[7] = f2b(b.w);
        *(u16x8*)(Xb + i) = r;
    } else {
        __shared__ float tile[32][33];
        int bid = blockIdx.x - 4096;        // 0..511 = 32 x 16
        int c0 = (bid & 31) * 32;           // col block in W (1024 cols)
        int r0 = (bid >> 5) * 32;           // row block in W (512 rows)
        int tx = threadIdx.x & 31;
        int ty = threadIdx.x >> 5;          // 0..7
        #pragma unroll
        for (int i = 0; i < 4; ++i) {
            int r = ty + i * 8;
            tile[r][tx] = W[(size_t)(r0 + r) * 1024 + c0 + tx];
        }
        __syncthreads();
        #pragma unroll
        for (int i = 0; i < 4; ++i) {
            int r = ty + i * 8;
            WT[(size_t)(c0 + r) * 512 + r0 + tx] = f2b(tile[tx][r]);
        }
    }
}

// ---------------- GEMM: Xb[16384,512](bf16) x WT[1024,512](bf16) + bias,
//                  elu+1; cols<512 -> Q (f32, in d_out), cols>=512 -> K (bf16)
// LDS XOR-swizzle: LDS chunk c of row r holds global chunk c ^ (r&7)
__global__ __launch_bounds__(256)
void k_gemm(const u16* __restrict__ Xb, const u16* __restrict__ WT,
            const float* __restrict__ bqk,
            float* __restrict__ Qo, u16* __restrict__ Kb) {
    __shared__ u16 As[128 * 64];   // unpadded: required by global_load_lds
    __shared__ u16 Bs[128 * 64];
    const int t = threadIdx.x;
    const int m0 = blockIdx.x * 128;
    const int n0 = blockIdx.y * 128;
    const int lane = t & 63;
    const int wave = t >> 6;
    const int wm = (wave >> 1) * 64;
    const int wn = (wave & 1) * 64;
    const int quad = lane >> 4;
    const int l16 = lane & 15;
    const int lr = lane >> 3;                   // 0..7: row within 8-row group
    const int cg = ((lane & 7) ^ lr) * 8;       // swizzled global chunk offset

    f32x4 acc[4][4];
    f32x4 zero4 = {0.f, 0.f, 0.f, 0.f};
    #pragma unroll
    for (int i = 0; i < 4; ++i)
        #pragma unroll
        for (int j = 0; j < 4; ++j) acc[i][j] = zero4;

    for (int k0 = 0; k0 < 512; k0 += 64) {
        __syncthreads();   // previous tile's LDS reads done
        #pragma unroll
        for (int g = 0; g < 4; ++g) {
            int r0 = wave * 32 + g * 8;
            size_t ga = (size_t)(m0 + r0 + lr) * 512 + k0 + cg;
            size_t gb = (size_t)(n0 + r0 + lr) * 512 + k0 + cg;
            gload_lds(Xb + ga, &As[r0 * 64]);
            gload_lds(WT + gb, &Bs[r0 * 64]);
        }
        __syncthreads();   // drains vmcnt -> staged data visible
        #pragma unroll
        for (int ks = 0; ks < 64; ks += 32) {
            const int cbase = quad + (ks >> 3);       // global chunk 0..7
            s16x8 a4[4], b4[4];
            #pragma unroll
            for (int i = 0; i < 4; ++i) {
                int row = wm + i * 16 + l16;
                a4[i] = *(const s16x8*)&As[row * 64 + ((cbase ^ (row & 7)) * 8)];
            }
            #pragma unroll
            for (int j = 0; j < 4; ++j) {
                int row = wn + j * 16 + l16;
                b4[j] = *(const s16x8*)&Bs[row * 64 + ((cbase ^ (row & 7)) * 8)];
            }
            #pragma unroll
            for (int i = 0; i < 4; ++i)
                #pragma unroll
                for (int j = 0; j < 4; ++j)
                    acc[i][j] = __builtin_amdgcn_mfma_f32_16x16x32_bf16(
                        a4[i], b4[j], acc[i][j], 0, 0, 0);
        }
    }

    const bool isQ = (n0 < 512);   // block-uniform
    #pragma unroll
    for (int i = 0; i < 4; ++i)
        #pragma unroll
        for (int j = 0; j < 4; ++j) {
            int col = n0 + wn + j * 16 + l16;
            float bias = bqk[col];
            int gc = col & 511;
            #pragma unroll
            for (int r = 0; r < 4; ++r) {
                int grow = m0 + wm + i * 16 + quad * 4 + r;
                float v = acc[i][j][r] + bias;
                v = v > 0.f ? v + 1.f : __expf(v);   // elu(v)+1
                if (isQ) Qo[(size_t)grow * 512 + gc] = v;
                else     Kb[(size_t)grow * 512 + gc] = f2b(v);
            }
        }
}

// ---------------- kv[b,h,d,e] = sum_n k_rope*v ; ksum[b,h,d] = sum_n k ------
__global__ __launch_bounds__(256)
void k_kv(const u16* __restrict__ Kb, const u16* __restrict__ Xb,
          float* __restrict__ kvbuf, float* __restrict__ ksum) {
    const int bh = blockIdx.x;            // 0..63
    const int b = bh >> 4, h = bh & 15;
    const int nb = blockIdx.y * 512;      // N chunk
    __shared__ float kr_s[64 * 32];
    __shared__ float v_s[64 * 32];
    const int t = threadIdx.x;
    const int row = t >> 2;               // 0..63 (staging row)
    const int c8 = (t & 3) * 8;           // channel chunk
    const int d = t >> 3;                 // 0..31 (compute)
    const int e0 = (t & 7) * 4;
    float ksl[8] = {0, 0, 0, 0, 0, 0, 0, 0};
    float acc[4] = {0, 0, 0, 0};

    float th[4];
    #pragma unroll
    for (int p = 0; p < 4; ++p)
        th[p] = exp2f(-THETA_SCALE * (float)(h * 16 + (c8 >> 1) + p));

    for (int pass = 0; pass < 8; ++pass) {
        int n = nb + pass * 64 + row;
        size_t base = (size_t)(b * 4096 + n) * 512 + h * 32 + c8;
        u16x8 k8 = *(const u16x8*)(Kb + base);
        u16x8 v8 = *(const u16x8*)(Xb + base);
        float kf[8], vf[8], kr[8];
        #pragma unroll
        for (int j = 0; j < 8; ++j) { kf[j] = b2f(k8[j]); vf[j] = b2f(v8[j]); }
        #pragma unroll
        for (int p = 0; p < 4; ++p) {
            float sv, cv;
            sincosf((float)n * th[p], &sv, &cv);
            kr[2 * p]     = kf[2 * p] * cv - kf[2 * p + 1] * sv;
            kr[2 * p + 1] = kf[2 * p] * sv + kf[2 * p + 1] * cv;
        }
        #pragma unroll
        for (int j = 0; j < 8; ++j) ksl[j] += kf[j];
        if (pass) __syncthreads();
        *(float4*)&kr_s[row * 32 + c8]     = make_float4(kr[0], kr[1], kr[2], kr[3]);
        *(float4*)&kr_s[row * 32 + c8 + 4] = make_float4(kr[4], kr[5], kr[6], kr[7]);
        *(float4*)&v_s[row * 32 + c8]      = make_float4(vf[0], vf[1], vf[2], vf[3]);
        *(float4*)&v_s[row * 32 + c8 + 4]  = make_float4(vf[4], vf[5], vf[6], vf[7]);
        __syncthreads();
        #pragma unroll 8
        for (int r = 0; r < 64; ++r) {
            float kd = kr_s[r * 32 + d];
            const float4 vv = *(const float4*)&v_s[r * 32 + e0];
            acc[0] += kd * vv.x;
            acc[1] += kd * vv.y;
            acc[2] += kd * vv.z;
            acc[3] += kd * vv.w;
        }
    }
    __syncthreads();
    *(float4*)&kr_s[row * 32 + c8]     = make_float4(ksl[0], ksl[1], ksl[2], ksl[3]);
    *(float4*)&kr_s[row * 32 + c8 + 4] = make_float4(ksl[4], ksl[5], ksl[6], ksl[7]);
    __syncthreads();
    if (t < 32) {
        float s = 0.f;
        for (int r = 0; r < 64; ++r) s += kr_s[r * 32 + t];
        atomicAdd(&ksum[bh * 32 + t], s);
    }
    #pragma unroll
    for (int j = 0; j < 4; ++j)
        atomicAdd(&kvbuf[(size_t)bh * 1024 + d * 32 + e0 + j], acc[j]);
}

// ---------------- out = z * (q_rope @ kv)/N + lepe (f32 in/out in d_out) ----
__global__ __launch_bounds__(256)
void k_out(float* QO, const u16* __restrict__ Xb,
           const float* __restrict__ kvbuf, const float* __restrict__ ksum,
           const float* __restrict__ lw, const float* __restrict__ lb) {
    const int b = blockIdx.x >> 6;
    const int nb = (blockIdx.x & 63) * 64;
    const int hbase = blockIdx.y * 4;
    __shared__ float kv_s[32 * 36];
    __shared__ float qr_s[64 * 36];
    __shared__ float ks_s[32];
    __shared__ float z_s[64];
    const int t = threadIdx.x;
    const int row = t >> 2;          // 0..63 local n
    const int c4 = t & 3;
    const int e0 = c4 * 8;
    const float invN = 1.f / 4096.f;
    const int n = nb + row;
    const size_t rowbase = (size_t)(b * 4096 + n) * 512;

    for (int hh = 0; hh < 4; ++hh) {
        const int h = hbase + hh;
        const int bh = b * 16 + h;
        if (hh) __syncthreads();               // protect LDS reuse
        #pragma unroll
        for (int i = 0; i < 4; ++i) {
            int id = t + i * 256;              // 0..1023
            kv_s[(id >> 5) * 36 + (id & 31)] = kvbuf[(size_t)bh * 1024 + id] * invN;
        }
        if (t < 32) ks_s[t] = ksum[bh * 32 + t] * invN;   // kmean
        __syncthreads();

        // phase 1: q (f32 from d_out), z partial dot, rope, stage q_rope
        const float* qp = QO + rowbase + h * 32 + e0;
        float4 q0 = *(const float4*)qp;
        float4 q1 = *(const float4*)(qp + 4);
        float qf[8] = {q0.x, q0.y, q0.z, q0.w, q1.x, q1.y, q1.z, q1.w};
        float part = 0.f;
        #pragma unroll
        for (int j = 0; j < 8; ++j) part += qf[j] * ks_s[e0 + j];
        float qr[8];
        #pragma unroll
        for (int p = 0; p < 4; ++p) {
            float th = exp2f(-THETA_SCALE * (float)(h * 16 + c4 * 4 + p));
            float sv, cv;
            sincosf((float)n * th, &sv, &cv);
            qr[2 * p]     = qf[2 * p] * cv - qf[2 * p + 1] * sv;
            qr[2 * p + 1] = qf[2 * p] * sv + qf[2 * p + 1] * cv;
        }
        *(float4*)&qr_s[row * 36 + e0]     = make_float4(qr[0], qr[1], qr[2], qr[3]);
        *(float4*)&qr_s[row * 36 + e0 + 4] = make_float4(qr[4], qr[5], qr[6], qr[7]);
        part += __shfl_xor(part, 1);
        part += __shfl_xor(part, 2);
        if (c4 == 0) z_s[row] = 1.f / (part + 1e-6f);
        __syncthreads();

        // phase 2: out[e0..e0+7] = z * sum_d qr[d]*kv[d][e]
        float o[8] = {0, 0, 0, 0, 0, 0, 0, 0};
        #pragma unroll 4
        for (int dd = 0; dd < 32; ++dd) {
            float qd = qr_s[row * 36 + dd];
            const float4 k0v = *(const float4*)&kv_s[dd * 36 + e0];
            const float4 k1v = *(const float4*)&kv_s[dd * 36 + e0 + 4];
            o[0] += qd * k0v.x; o[1] += qd * k0v.y; o[2] += qd * k0v.z; o[3] += qd * k0v.w;
            o[4] += qd * k1v.x; o[5] += qd * k1v.y; o[6] += qd * k1v.z; o[7] += qd * k1v.w;
        }
        const float z = z_s[row];

        // lepe: depthwise conv k=3, pad 1 (per-batch), + bias; x via Xb bf16
        const int cb = h * 32 + e0;
        u16x8 xc = *(const u16x8*)(Xb + rowbase + cb);
        u16x8 xm = {0, 0, 0, 0, 0, 0, 0, 0};
        u16x8 xp = {0, 0, 0, 0, 0, 0, 0, 0};
        if (n > 0)    xm = *(const u16x8*)(Xb + rowbase - 512 + cb);
        if (n < 4095) xp = *(const u16x8*)(Xb + rowbase + 512 + cb);
        float rv[8];
        #pragma unroll
        for (int j = 0; j < 8; ++j) {
            int c = cb + j;
            float lep = b2f(xm[j]) * lw[c * 3] +
                        b2f(xc[j]) * lw[c * 3 + 1] +
                        b2f(xp[j]) * lw[c * 3 + 2] + lb[c];
            rv[j] = o[j] * z + lep;
        }
        float* Of = QO + rowbase + cb;   // same thread read q above -> safe
        *(float4*)Of       = make_float4(rv[0], rv[1], rv[2], rv[3]);
        *(float4*)(Of + 4) = make_float4(rv[4], rv[5], rv[6], rv[7]);
    }
}

extern "C" void kernel_launch(void* const* d_in, const int* in_sizes, int n_in,
                              void* d_out, int out_size, void* d_ws, size_t ws_size,
                              hipStream_t stream) {
    const float* x   = (const float*)d_in[0];   // (4,4096,512) f32
    const float* Wqk = (const float*)d_in[1];   // (512,1024)
    const float* bqk = (const float*)d_in[2];   // (1024,)
    const float* lw  = (const float*)d_in[3];   // (512,1,3)
    const float* lb  = (const float*)d_in[4];   // (512,)
    float* out = (float*)d_out;                 // Q then final output (32 MB)

    // workspace layout (~33.3 MB)
    char* w = (char*)d_ws;
    u16* Kb      = (u16*)w;   w += (size_t)16384 * 512 * 2;   // 16 MB
    u16* Xb      = (u16*)w;   w += (size_t)16384 * 512 * 2;   // 16 MB
    u16* WT      = (u16*)w;   w += (size_t)1024 * 512 * 2;    // 1 MB
    float* kvbuf = (float*)w; w += (size_t)64 * 1024 * 4;     // 256 KB
    float* ksum  = (float*)w;                                 // 8 KB

    hipMemsetAsync(kvbuf, 0, (size_t)64 * 1024 * 4 + (size_t)64 * 32 * 4, stream);
    k_prep<<<4608, 256, 0, stream>>>(x, Xb, Wqk, WT);
    k_gemm<<<dim3(128, 8), 256, 0, stream>>>(Xb, WT, bqk, out, Kb);
    k_kv<<<dim3(64, 8), 256, 0, stream>>>(Kb, Xb, kvbuf, ksum);
    k_out<<<dim3(256, 4), 256, 0, stream>>>(out, Xb, kvbuf, ksum, lw, lb);
}